// Round 1
// baseline (483.929 us; speedup 1.0000x reference)
//
#include <hip/hip_runtime.h>
#include <cstdint>
#include <cstddef>

typedef __attribute__((ext_vector_type(8))) short short8;
typedef __attribute__((ext_vector_type(4))) float f32x4;
typedef unsigned int u32;

#define MFMA_BF16(a, b, c) __builtin_amdgcn_mfma_f32_16x16x32_bf16((a), (b), (c), 0, 0, 0)

// ---------------------------------------------------------------------------
// helpers
// ---------------------------------------------------------------------------
__device__ __forceinline__ void async16(const void* g, void* l) {
  __builtin_amdgcn_global_load_lds(
      (const __attribute__((address_space(1))) u32*)g,
      (__attribute__((address_space(3))) u32*)l, 16, 0, 0);
}

__device__ __forceinline__ short f2bf(float f) {
  u32 u = __builtin_bit_cast(u32, f);
  u += 0x7fffu + ((u >> 16) & 1u);  // round-to-nearest-even
  return (short)(u >> 16);
}

// ---------------------------------------------------------------------------
// cast fp32 -> bf16 (stored as short), 4 elements/thread
// ---------------------------------------------------------------------------
__global__ void cast_bf16_kernel(const float* __restrict__ in,
                                 short* __restrict__ out, int n4) {
  int i = blockIdx.x * blockDim.x + threadIdx.x;
  if (i < n4) {
    float4 v = ((const float4*)in)[i];
    short4 r;
    r.x = f2bf(v.x); r.y = f2bf(v.y); r.z = f2bf(v.z); r.w = f2bf(v.w);
    ((short4*)out)[i] = r;
  }
}

// ---------------------------------------------------------------------------
// C[M][N] = A[M][K] * Bt[N][K]^T      (all bf16-as-short, fp32 accumulate)
// m97-style: 128x128 block tile, BK=32, global_load_lds width 16,
// 4 waves in 2x2, each wave 64x64 via 4x4 grid of 16x16x32 MFMAs.
// M,N divisible by 128; K divisible by 32.
// ---------------------------------------------------------------------------
template <bool OUT_BF16>
__global__ __launch_bounds__(256) void gemm_bt_kernel(
    const short* __restrict__ A, const short* __restrict__ Bt,
    void* __restrict__ Cv, int M, int N, int K) {
  __shared__ __align__(16) short As[128 * 32];
  __shared__ __align__(16) short Bs[128 * 32];

  const int tid  = threadIdx.x;
  const int lane = tid & 63;
  const int wave = tid >> 6;
  const int quad = lane >> 4;
  const int l15  = lane & 15;
  const int bm   = blockIdx.y * 128;
  const int bn   = blockIdx.x * 128;
  const int wm   = (wave >> 1) * 64;
  const int wn   = (wave & 1) * 64;

  f32x4 acc[4][4];
#pragma unroll
  for (int i = 0; i < 4; ++i)
#pragma unroll
    for (int j = 0; j < 4; ++j) acc[i][j] = (f32x4){0.f, 0.f, 0.f, 0.f};

  // staging: 128 rows x 32 cols x 2B = 8 KB = 512 chunks of 16 B; 2/thread
  const int ci0 = tid, ci1 = tid + 256;
  const short* ga0 = A  + (size_t)(bm + (ci0 >> 2)) * K + (ci0 & 3) * 8;
  const short* ga1 = A  + (size_t)(bm + (ci1 >> 2)) * K + (ci1 & 3) * 8;
  const short* gb0 = Bt + (size_t)(bn + (ci0 >> 2)) * K + (ci0 & 3) * 8;
  const short* gb1 = Bt + (size_t)(bn + (ci1 >> 2)) * K + (ci1 & 3) * 8;

  for (int k0 = 0; k0 < K; k0 += 32) {
    __syncthreads();  // previous iteration's LDS reads done
    async16(ga0 + k0, &As[ci0 * 8]);
    async16(ga1 + k0, &As[ci1 * 8]);
    async16(gb0 + k0, &Bs[ci0 * 8]);
    async16(gb1 + k0, &Bs[ci1 * 8]);
    __syncthreads();  // staging complete (drains vmcnt)

    short8 af[4], bf[4];
#pragma unroll
    for (int mt = 0; mt < 4; ++mt)
      af[mt] = *(const short8*)&As[(wm + mt * 16 + l15) * 32 + quad * 8];
#pragma unroll
    for (int nt = 0; nt < 4; ++nt)
      bf[nt] = *(const short8*)&Bs[(wn + nt * 16 + l15) * 32 + quad * 8];
#pragma unroll
    for (int mt = 0; mt < 4; ++mt)
#pragma unroll
      for (int nt = 0; nt < 4; ++nt)
        acc[mt][nt] = MFMA_BF16(af[mt], bf[nt], acc[mt][nt]);
  }

  // epilogue: C/D layout col = lane&15, row = quad*4 + reg
#pragma unroll
  for (int mt = 0; mt < 4; ++mt) {
    const int r0 = bm + wm + mt * 16 + quad * 4;
#pragma unroll
    for (int nt = 0; nt < 4; ++nt) {
      const int c = bn + wn + nt * 16 + l15;
#pragma unroll
      for (int reg = 0; reg < 4; ++reg) {
        float v = acc[mt][nt][reg];
        if (OUT_BF16)
          ((short*)Cv)[(size_t)(r0 + reg) * N + c] = f2bf(v);
        else
          ((float*)Cv)[(size_t)(r0 + reg) * N + c] = v;
      }
    }
  }
}

// ---------------------------------------------------------------------------
// Causal flash attention over bf16 qkv [B*T, 3C] (q | k | v each C=1024).
// grid = (T/64, B*H); block = 256 (4 waves). Wave w owns q-rows
// qt*64 + w*16 .. +16. Iterates kv-tiles of 64, online softmax.
// Output y: bf16 [B*T, C] with head-major cols (b,t,h,d) -> ready for proj.
// ---------------------------------------------------------------------------
__global__ __launch_bounds__(256) void attn_kernel(
    const short* __restrict__ qkv, short* __restrict__ y) {
  const int qt = blockIdx.x;       // 0..31 (q tile of 64)
  const int bh = blockIdx.y;       // 0..63
  const int b  = bh >> 4;
  const int h  = bh & 15;

  const int tid  = threadIdx.x;
  const int lane = tid & 63;
  const int wave = tid >> 6;
  const int quad = lane >> 4;
  const int l15  = lane & 15;

  // K tile as [kk][t][32] (matches GEMM LDS pattern -> 2-way free conflicts)
  __shared__ __align__(16) short Ks[2 * 64 * 32];
  // V transposed [d][t], row stride 72 (pad: breaks 16-stride bank aliasing,
  // keeps 16B alignment: 72*2=144 bytes)
  __shared__ __align__(16) short Vs[64 * 72];
  // per-wave P tile [16][72]
  __shared__ __align__(16) short Ps[4][16 * 72];

  const size_t rs3c = 3072;        // qkv row stride (elements)
  const int base_row = b * 2048;

  // Q fragments (A-operand, 16 rows x 64 k): held in registers for all iters
  short8 qf[2];
  {
    const int qrow = base_row + qt * 64 + wave * 16 + l15;
    const short* qp = qkv + (size_t)qrow * rs3c + h * 64 + quad * 8;
    qf[0] = *(const short8*)qp;
    qf[1] = *(const short8*)(qp + 32);
  }

  float m_r[4], l_r[4];
  f32x4 o[4];
#pragma unroll
  for (int r = 0; r < 4; ++r) { m_r[r] = -INFINITY; l_r[r] = 0.f; }
#pragma unroll
  for (int dt = 0; dt < 4; ++dt) o[dt] = (f32x4){0.f, 0.f, 0.f, 0.f};

  const float kscale = 0.125f * 1.44269504f;  // 1/sqrt(64) * log2(e)
  const int qrow_loc0 = qt * 64 + wave * 16 + quad * 4;  // + reg (seq index)

  for (int kt = 0; kt <= qt; ++kt) {
    __syncthreads();  // previous iteration's Vs/Ps reads complete

    // ---- stage K tile: 512 chunks of 16B, 2 per thread, layout [kk][t][32]
#pragma unroll
    for (int it = 0; it < 2; ++it) {
      const int ci = tid + 256 * it;
      const int kk = ci >> 8, t = (ci >> 2) & 63, cw = ci & 3;
      const short* src = qkv + (size_t)(base_row + kt * 64 + t) * rs3c +
                         1024 + h * 64 + kk * 32 + cw * 8;
      async16(src, &Ks[ci * 8]);
    }
    // ---- stage V transposed: thread covers column d = tid&63,
    // rows t0..t0+15; global reads coalesce (64 lanes = 128B per row)
    {
      const int d  = tid & 63;
      const int t0 = (tid >> 6) * 16;
#pragma unroll
      for (int half = 0; half < 2; ++half) {
        short tmp[8];
#pragma unroll
        for (int j = 0; j < 8; ++j) {
          const int t = t0 + half * 8 + j;
          tmp[j] = qkv[(size_t)(base_row + kt * 64 + t) * rs3c + 2048 + h * 64 + d];
        }
        *(short8*)&Vs[d * 72 + t0 + half * 8] = *(short8*)tmp;
      }
    }
    __syncthreads();  // staging complete

    // ---- S = Q K^T (16 q x 64 kv per wave)
    f32x4 s[4];
#pragma unroll
    for (int nt = 0; nt < 4; ++nt) {
      s[nt] = (f32x4){0.f, 0.f, 0.f, 0.f};
      short8 kf0 = *(const short8*)&Ks[(nt * 16 + l15) * 32 + quad * 8];
      short8 kf1 = *(const short8*)&Ks[2048 + (nt * 16 + l15) * 32 + quad * 8];
      s[nt] = MFMA_BF16(qf[0], kf0, s[nt]);
      s[nt] = MFMA_BF16(qf[1], kf1, s[nt]);
    }

    // ---- scale + causal mask (in log2 domain)
    float xs[4][4];
    const int col0 = kt * 64 + l15;
#pragma unroll
    for (int nt = 0; nt < 4; ++nt)
#pragma unroll
      for (int reg = 0; reg < 4; ++reg) {
        float v = s[nt][reg] * kscale;
        if (col0 + nt * 16 > qrow_loc0 + reg) v = -INFINITY;
        xs[nt][reg] = v;
      }

    // ---- online softmax: row max via 16-lane butterfly
    float mnew[4], alpha[4];
#pragma unroll
    for (int reg = 0; reg < 4; ++reg) {
      float t = fmaxf(fmaxf(xs[0][reg], xs[1][reg]), fmaxf(xs[2][reg], xs[3][reg]));
      t = fmaxf(t, __shfl_xor(t, 1));
      t = fmaxf(t, __shfl_xor(t, 2));
      t = fmaxf(t, __shfl_xor(t, 4));
      t = fmaxf(t, __shfl_xor(t, 8));
      mnew[reg]  = fmaxf(m_r[reg], t);
      alpha[reg] = exp2f(m_r[reg] - mnew[reg]);  // m_r=-inf -> 0
      m_r[reg]   = mnew[reg];
    }

    // ---- P = exp2(xs - mnew), row sums, pack bf16
    float rsum[4] = {0.f, 0.f, 0.f, 0.f};
    short pb[4][4];
#pragma unroll
    for (int nt = 0; nt < 4; ++nt)
#pragma unroll
      for (int reg = 0; reg < 4; ++reg) {
        float p = exp2f(xs[nt][reg] - mnew[reg]);
        rsum[reg] += p;
        pb[nt][reg] = f2bf(p);
      }
#pragma unroll
    for (int reg = 0; reg < 4; ++reg) {
      float t = rsum[reg];
      t += __shfl_xor(t, 1);
      t += __shfl_xor(t, 2);
      t += __shfl_xor(t, 4);
      t += __shfl_xor(t, 8);
      l_r[reg] = l_r[reg] * alpha[reg] + t;
    }

    // ---- rescale O accumulator
#pragma unroll
    for (int dt = 0; dt < 4; ++dt)
#pragma unroll
      for (int reg = 0; reg < 4; ++reg) o[dt][reg] *= alpha[reg];

    // ---- write P (C-layout) to LDS for A-layout reread
    short* myP = &Ps[wave][0];
#pragma unroll
    for (int nt = 0; nt < 4; ++nt)
#pragma unroll
      for (int reg = 0; reg < 4; ++reg)
        myP[(quad * 4 + reg) * 72 + nt * 16 + l15] = pb[nt][reg];
    __syncthreads();  // P visible (and all waves aligned)

    // ---- O += P V
    short8 pf0 = *(const short8*)&myP[l15 * 72 + quad * 8];
    short8 pf1 = *(const short8*)&myP[l15 * 72 + 32 + quad * 8];
#pragma unroll
    for (int dt = 0; dt < 4; ++dt) {
      short8 vf0 = *(const short8*)&Vs[(dt * 16 + l15) * 72 + quad * 8];
      short8 vf1 = *(const short8*)&Vs[(dt * 16 + l15) * 72 + 32 + quad * 8];
      o[dt] = MFMA_BF16(pf0, vf0, o[dt]);
      o[dt] = MFMA_BF16(pf1, vf1, o[dt]);
    }
  }

  // ---- epilogue: O /= l, write bf16 y[b*T + t][h*64 + d]
  float inv[4];
#pragma unroll
  for (int reg = 0; reg < 4; ++reg) inv[reg] = 1.f / l_r[reg];
#pragma unroll
  for (int dt = 0; dt < 4; ++dt) {
    const int col = h * 64 + dt * 16 + l15;
#pragma unroll
    for (int reg = 0; reg < 4; ++reg) {
      const int row = base_row + qt * 64 + wave * 16 + quad * 4 + reg;
      y[(size_t)row * 1024 + col] = f2bf(o[dt][reg] * inv[reg]);
    }
  }
}

// ---------------------------------------------------------------------------
// launch
// ---------------------------------------------------------------------------
extern "C" void kernel_launch(void* const* d_in, const int* in_sizes, int n_in,
                              void* d_out, int out_size, void* d_ws,
                              size_t ws_size, hipStream_t stream) {
  const float* x  = (const float*)d_in[0];   // [4,2048,1024]
  const float* wa = (const float*)d_in[1];   // [3072,1024]
  const float* wp = (const float*)d_in[2];   // [1024,1024]
  float* out = (float*)d_out;                // [4,2048,1024] fp32

  char* ws = (char*)d_ws;
  short* xb  = (short*)(ws + 0);             // 16 MB
  short* wab = (short*)(ws + 16777216);      // 6 MB
  short* wpb = (short*)(ws + 23068672);      // 2 MB
  short* qkv = (short*)(ws + 25165824);      // 48 MB
  short* yb  = (short*)(ws + 75497472);      // 16 MB
  // total ws use: 92,274,688 B

  // casts
  cast_bf16_kernel<<<8192, 256, 0, stream>>>(x,  xb,  8388608 / 4);
  cast_bf16_kernel<<<3072, 256, 0, stream>>>(wa, wab, 3145728 / 4);
  cast_bf16_kernel<<<1024, 256, 0, stream>>>(wp, wpb, 1048576 / 4);

  // qkv = x @ w_attn^T : M=8192 N=3072 K=1024 -> bf16
  gemm_bt_kernel<true><<<dim3(3072 / 128, 8192 / 128), 256, 0, stream>>>(
      xb, wab, (void*)qkv, 8192, 3072, 1024);

  // causal flash attention -> y bf16 [8192,1024]
  attn_kernel<<<dim3(32, 64), 256, 0, stream>>>(qkv, yb);

  // out = y @ w_proj^T : M=8192 N=1024 K=1024 -> fp32
  gemm_bt_kernel<false><<<dim3(1024 / 128, 8192 / 128), 256, 0, stream>>>(
      yb, wpb, (void*)out, 8192, 1024, 1024);
}

// Round 3
// 284.038 us; speedup vs baseline: 1.7037x; 1.7037x over previous
//
#include <hip/hip_runtime.h>
#include <cstdint>
#include <cstddef>

typedef __attribute__((ext_vector_type(8))) short short8;
typedef __attribute__((ext_vector_type(4))) float f32x4;
typedef unsigned int u32;

#define MFMA_BF16(a, b, c) __builtin_amdgcn_mfma_f32_16x16x32_bf16((a), (b), (c), 0, 0, 0)

// ---------------------------------------------------------------------------
// helpers
// ---------------------------------------------------------------------------
__device__ __forceinline__ void async16(const void* g, void* l) {
  __builtin_amdgcn_global_load_lds(
      (const __attribute__((address_space(1))) u32*)g,
      (__attribute__((address_space(3))) u32*)l, 16, 0, 0);
}

__device__ __forceinline__ short f2bf(float f) {
  u32 u = __builtin_bit_cast(u32, f);
  u += 0x7fffu + ((u >> 16) & 1u);  // round-to-nearest-even
  return (short)(u >> 16);
}

// truncating pack: [bf16(lo) | bf16(hi)<<16] in ONE v_perm_b32
__device__ __forceinline__ u32 pack_bf16_trunc(float lo, float hi) {
  return __builtin_amdgcn_perm(__builtin_bit_cast(u32, hi),
                               __builtin_bit_cast(u32, lo), 0x07060302u);
}

// ---------------------------------------------------------------------------
// cast fp32 -> bf16; scale variant folds attn scale into q-rows of w_attn
// ---------------------------------------------------------------------------
__global__ void cast_bf16_kernel(const float* __restrict__ in,
                                 short* __restrict__ out, int n4) {
  int i = blockIdx.x * blockDim.x + threadIdx.x;
  if (i < n4) {
    float4 v = ((const float4*)in)[i];
    short4 r;
    r.x = f2bf(v.x); r.y = f2bf(v.y); r.z = f2bf(v.z); r.w = f2bf(v.w);
    ((short4*)out)[i] = r;
  }
}

// w_attn [3072][1024]; rows < 1024 (q) scaled by 1/sqrt(64)*log2(e)
__global__ void cast_wattn_kernel(const float* __restrict__ in,
                                  short* __restrict__ out, int n4) {
  int i = blockIdx.x * blockDim.x + threadIdx.x;
  if (i < n4) {
    const float sc = (i * 4 < 1024 * 1024) ? 0.18033688011112042f : 1.0f;
    float4 v = ((const float4*)in)[i];
    short4 r;
    r.x = f2bf(v.x * sc); r.y = f2bf(v.y * sc);
    r.z = f2bf(v.z * sc); r.w = f2bf(v.w * sc);
    ((short4*)out)[i] = r;
  }
}

// ---------------------------------------------------------------------------
// C[M][N] = A[M][K] * Bt[N][K]^T   (bf16-as-short in, fp32 accumulate)
// m97 structure: 128x128 tile, BK=32, global_load_lds w=16, 16x16x32 MFMA.
// ---------------------------------------------------------------------------
template <bool OUT_BF16>
__global__ __launch_bounds__(256) void gemm_bt_kernel(
    const short* __restrict__ A, const short* __restrict__ Bt,
    void* __restrict__ Cv, int M, int N, int K) {
  __shared__ __align__(16) short As[128 * 32];
  __shared__ __align__(16) short Bs[128 * 32];

  const int tid  = threadIdx.x;
  const int lane = tid & 63;
  const int wave = tid >> 6;
  const int quad = lane >> 4;
  const int l15  = lane & 15;
  const int bm   = blockIdx.y * 128;
  const int bn   = blockIdx.x * 128;
  const int wm   = (wave >> 1) * 64;
  const int wn   = (wave & 1) * 64;

  f32x4 acc[4][4];
#pragma unroll
  for (int i = 0; i < 4; ++i)
#pragma unroll
    for (int j = 0; j < 4; ++j) acc[i][j] = (f32x4){0.f, 0.f, 0.f, 0.f};

  const int ci0 = tid, ci1 = tid + 256;
  const short* ga0 = A  + (size_t)(bm + (ci0 >> 2)) * K + (ci0 & 3) * 8;
  const short* ga1 = A  + (size_t)(bm + (ci1 >> 2)) * K + (ci1 & 3) * 8;
  const short* gb0 = Bt + (size_t)(bn + (ci0 >> 2)) * K + (ci0 & 3) * 8;
  const short* gb1 = Bt + (size_t)(bn + (ci1 >> 2)) * K + (ci1 & 3) * 8;

  for (int k0 = 0; k0 < K; k0 += 32) {
    __syncthreads();
    async16(ga0 + k0, &As[ci0 * 8]);
    async16(ga1 + k0, &As[ci1 * 8]);
    async16(gb0 + k0, &Bs[ci0 * 8]);
    async16(gb1 + k0, &Bs[ci1 * 8]);
    __syncthreads();

    short8 af[4], bf[4];
#pragma unroll
    for (int mt = 0; mt < 4; ++mt)
      af[mt] = *(const short8*)&As[(wm + mt * 16 + l15) * 32 + quad * 8];
#pragma unroll
    for (int nt = 0; nt < 4; ++nt)
      bf[nt] = *(const short8*)&Bs[(wn + nt * 16 + l15) * 32 + quad * 8];
#pragma unroll
    for (int mt = 0; mt < 4; ++mt)
#pragma unroll
      for (int nt = 0; nt < 4; ++nt)
        acc[mt][nt] = MFMA_BF16(af[mt], bf[nt], acc[mt][nt]);
  }

#pragma unroll
  for (int mt = 0; mt < 4; ++mt) {
    const int r0 = bm + wm + mt * 16 + quad * 4;
#pragma unroll
    for (int nt = 0; nt < 4; ++nt) {
      const int c = bn + wn + nt * 16 + l15;
#pragma unroll
      for (int reg = 0; reg < 4; ++reg) {
        float v = acc[mt][nt][reg];
        if (OUT_BF16)
          ((short*)Cv)[(size_t)(r0 + reg) * N + c] = f2bf(v);
        else
          ((float*)Cv)[(size_t)(r0 + reg) * N + c] = v;
      }
    }
  }
}

// ---------------------------------------------------------------------------
// V transpose: qkv v-part [B*T][h*64+d] -> vt [bh*64+d][T]   (bf16 shorts)
// grid (T/64, BH), block 256. LDS tile 64t x 64d, stride 80 (16B-aligned rows)
// 64x64 shorts = 512 chunks of 8 shorts: ci -> t=ci>>3, cw=ci&7.
// ---------------------------------------------------------------------------
__global__ __launch_bounds__(256) void vtrans_kernel(
    const short* __restrict__ qkv, short* __restrict__ vt) {
  __shared__ __align__(16) short Ts[64 * 80];
  const int t0 = blockIdx.x * 64;
  const int bh = blockIdx.y;
  const int b = bh >> 4, h = bh & 15;
  const int tid = threadIdx.x;
#pragma unroll
  for (int it = 0; it < 2; ++it) {
    const int ci = tid + it * 256;
    const int t = ci >> 3, cw = ci & 7;
    short8 v = *(const short8*)(qkv + (size_t)(b * 2048 + t0 + t) * 3072 +
                                2048 + h * 64 + cw * 8);
    *(short8*)&Ts[t * 80 + cw * 8] = v;
  }
  __syncthreads();
#pragma unroll
  for (int it = 0; it < 2; ++it) {
    const int ci = tid + it * 256;
    const int d = ci >> 3, c2 = ci & 7;
    short tmp[8];
#pragma unroll
    for (int j = 0; j < 8; ++j) tmp[j] = Ts[(c2 * 8 + j) * 80 + d];
    *(short8*)(vt + (size_t)(bh * 64 + d) * 2048 + t0 + c2 * 8) =
        *(short8*)tmp;
  }
}

// ---------------------------------------------------------------------------
// Causal flash attention, S^T formulation, no-max softmax (scale pre-folded
// into q via w_attn cast; exp2 domain). Block = 4 waves, q-tile 128 rows
// (2 groups of 16 per wave), kv-tile 64. Work-balanced: block processes
// q-tiles pairi and 15-pairi (34 equal kv-iterations). grid (8, 64).
// ---------------------------------------------------------------------------
__global__ __launch_bounds__(256, 2) void attn_kernel(
    const short* __restrict__ qkv, const short* __restrict__ vt,
    short* __restrict__ y) {
  __shared__ __align__(16) short Ks[2 * 64 * 32];  // [d-half][t 64][32]
  __shared__ __align__(16) short Vs[2 * 64 * 32];  // [t-half][d 64][32]
  __shared__ __align__(16) short Ps[4][1024];      // per-wave P / epilogue

  const int pairi = blockIdx.x;     // 0..7
  const int bh    = blockIdx.y;     // 0..63
  const int b = bh >> 4, h = bh & 15;
  const int tid  = threadIdx.x;
  const int lane = tid & 63;
  const int wave = tid >> 6;
  const int quad = lane >> 4, l15 = lane & 15;
  const int base_row = b * 2048;
  short* Pw = &Ps[wave][0];
  const int sw = l15 & 3;           // P chunk swizzle (bank spread)

  // staging constants: ci -> (kk=ci>>8, r=(ci>>2)&63, cw=ci&3), dst=ci*8
  const int ci0 = tid, ci1 = tid + 256;
  const short* kbase0 = qkv + (size_t)(base_row + ((ci0 >> 2) & 63)) * 3072 +
                        1024 + h * 64 + (ci0 >> 8) * 32 + (ci0 & 3) * 8;
  const short* kbase1 = qkv + (size_t)(base_row + ((ci1 >> 2) & 63)) * 3072 +
                        1024 + h * 64 + (ci1 >> 8) * 32 + (ci1 & 3) * 8;
  const short* vbase0 = vt + (size_t)(bh * 64 + ((ci0 >> 2) & 63)) * 2048 +
                        (ci0 >> 8) * 32 + (ci0 & 3) * 8;
  const short* vbase1 = vt + (size_t)(bh * 64 + ((ci1 >> 2) & 63)) * 2048 +
                        (ci1 >> 8) * 32 + (ci1 & 3) * 8;

  for (int half = 0; half < 2; ++half) {
    const int qi  = half ? (15 - pairi) : pairi;
    const int r0  = qi * 128;
    const int nkt = 2 * qi + 2;
    const int qg0a = r0 + wave * 32;   // group 0 q-base (seq-relative)
    const int qg0b = qg0a + 16;        // group 1

    // Q fragments (B-operand): lane holds Q[q=l15][d=quad*8..+7] per half
    short8 qf[2][2];
#pragma unroll
    for (int g = 0; g < 2; ++g) {
      const short* qp = qkv +
          (size_t)(base_row + qg0a + g * 16 + l15) * 3072 + h * 64 + quad * 8;
      qf[g][0] = *(const short8*)qp;
      qf[g][1] = *(const short8*)(qp + 32);
    }
    float l_r[2] = {0.f, 0.f};
    f32x4 o[2][4];
#pragma unroll
    for (int g = 0; g < 2; ++g)
#pragma unroll
      for (int dt = 0; dt < 4; ++dt) o[g][dt] = (f32x4){0.f, 0.f, 0.f, 0.f};

    for (int kt = 0; kt < nkt; ++kt) {
      const int kvb = kt * 64;
      __syncthreads();  // prev iteration's K/V reads complete
      async16(kbase0 + (size_t)kvb * 3072, &Ks[ci0 * 8]);
      async16(kbase1 + (size_t)kvb * 3072, &Ks[ci1 * 8]);
      async16(vbase0 + kvb, &Vs[ci0 * 8]);
      async16(vbase1 + kvb, &Vs[ci1 * 8]);
      __syncthreads();  // staging complete

      if (kvb <= qg0b + 15) {  // wave has any unmasked work
        // K fragments (A-operand): lane holds K[kv=nt*16+l15][d=quad*8..]
        short8 kf[4][2];
#pragma unroll
        for (int nt = 0; nt < 4; ++nt) {
          kf[nt][0] = *(const short8*)&Ks[(nt * 16 + l15) * 32 + quad * 8];
          kf[nt][1] = *(const short8*)&Ks[2048 + (nt * 16 + l15) * 32 + quad * 8];
        }
#pragma unroll
        for (int g = 0; g < 2; ++g) {
          const int qg0 = qg0a + g * 16;
          if (kvb > qg0 + 15) continue;  // group fully masked

          // S^T = K Q^T : lane gets S^T[kv=nt*16+quad*4+reg][q=l15]
          f32x4 s[4];
#pragma unroll
          for (int nt = 0; nt < 4; ++nt) {
            s[nt] = MFMA_BF16(kf[nt][0], qf[g][0], ((f32x4){0.f, 0.f, 0.f, 0.f}));
            s[nt] = MFMA_BF16(kf[nt][1], qf[g][1], s[nt]);
          }

          // p = exp2(s) (scale folded into q); mask only on diagonal tiles
          float p[4][4];
          if (kvb + 64 <= qg0) {
#pragma unroll
            for (int nt = 0; nt < 4; ++nt)
#pragma unroll
              for (int r = 0; r < 4; ++r)
                p[nt][r] = __builtin_amdgcn_exp2f(s[nt][r]);
          } else {
            const int qrel = qg0 + l15 - kvb;
#pragma unroll
            for (int nt = 0; nt < 4; ++nt)
#pragma unroll
              for (int r = 0; r < 4; ++r) {
                const int kvl = nt * 16 + quad * 4 + r;
                p[nt][r] = (kvl <= qrel) ? __builtin_amdgcn_exp2f(s[nt][r]) : 0.f;
              }
          }

          // row sum: 15 in-lane adds + 2 cross-quad shuffles
          float rs = ((p[0][0] + p[0][1]) + (p[0][2] + p[0][3])) +
                     ((p[1][0] + p[1][1]) + (p[1][2] + p[1][3])) +
                     ((p[2][0] + p[2][1]) + (p[2][2] + p[2][3])) +
                     ((p[3][0] + p[3][1]) + (p[3][2] + p[3][3]));
          rs += __shfl_xor(rs, 16);
          rs += __shfl_xor(rs, 32);
          l_r[g] += rs;

          // P^T -> LDS [kk][q=l15][32] with XOR chunk swizzle, packed b32
#pragma unroll
          for (int nt = 0; nt < 4; ++nt) {
            u32 w0 = pack_bf16_trunc(p[nt][0], p[nt][1]);
            u32 w1 = pack_bf16_trunc(p[nt][2], p[nt][3]);
            const int chunk = (nt & 1) * 2 + (quad >> 1);
            u32* dst = (u32*)Pw + (nt >> 1) * 256 + l15 * 16 +
                       (chunk ^ sw) * 4 + (quad & 1) * 2;
            dst[0] = w0;
            dst[1] = w1;
          }
          // P fragments (B-operand): lane reads P[q=l15][t=quad*8..] per half
          short8 pf0 = *(const short8*)&Pw[l15 * 32 + (quad ^ sw) * 8];
          short8 pf1 = *(const short8*)&Pw[512 + l15 * 32 + (quad ^ sw) * 8];

          // O^T += V^T P^T : lane gets O^T[d=dt*16+quad*4+reg][q=l15]
#pragma unroll
          for (int dt = 0; dt < 4; ++dt) {
            short8 vf0 = *(const short8*)&Vs[(dt * 16 + l15) * 32 + quad * 8];
            short8 vf1 = *(const short8*)&Vs[2048 + (dt * 16 + l15) * 32 + quad * 8];
            o[g][dt] = MFMA_BF16(vf0, pf0, o[g][dt]);
            o[g][dt] = MFMA_BF16(vf1, pf1, o[g][dt]);
          }
        }
      }
    }

    // epilogue: normalize, transpose via per-wave LDS, coalesced bf16 store
#pragma unroll
    for (int g = 0; g < 2; ++g) {
      const float inv = 1.f / l_r[g];
#pragma unroll
      for (int dt = 0; dt < 4; ++dt) {
        const int d = dt * 16 + quad * 4;
        u32 w0 = pack_bf16_trunc(o[g][dt][0] * inv, o[g][dt][1] * inv);
        u32 w1 = pack_bf16_trunc(o[g][dt][2] * inv, o[g][dt][3] * inv);
        *(uint2*)&Pw[(d >> 5) * 512 + l15 * 32 + (d & 31)] = make_uint2(w0, w1);
      }
      const int qq = lane >> 2, ck = lane & 3;
      const size_t yrow = (size_t)(base_row + qg0a + g * 16 + qq);
#pragma unroll
      for (int kkd = 0; kkd < 2; ++kkd) {
        short8 vv = *(const short8*)&Pw[kkd * 512 + qq * 32 + ck * 8];
        *(short8*)(y + yrow * 1024 + h * 64 + kkd * 32 + ck * 8) = vv;
      }
    }
  }
}

// ---------------------------------------------------------------------------
// launch
// ---------------------------------------------------------------------------
extern "C" void kernel_launch(void* const* d_in, const int* in_sizes, int n_in,
                              void* d_out, int out_size, void* d_ws,
                              size_t ws_size, hipStream_t stream) {
  const float* x  = (const float*)d_in[0];   // [4,2048,1024]
  const float* wa = (const float*)d_in[1];   // [3072,1024]
  const float* wp = (const float*)d_in[2];   // [1024,1024]
  float* out = (float*)d_out;                // [4,2048,1024] fp32

  char* ws = (char*)d_ws;
  short* xb  = (short*)(ws + 0);             // 16 MB (reused as vt later)
  short* wab = (short*)(ws + 16777216);      // 6 MB
  short* wpb = (short*)(ws + 23068672);      // 2 MB
  short* qkv = (short*)(ws + 25165824);      // 48 MB
  short* yb  = (short*)(ws + 75497472);      // 16 MB
  short* vtb = xb;  // x no longer needed after GEMM1; reuse its 16 MB

  cast_bf16_kernel <<<8192, 256, 0, stream>>>(x,  xb,  8388608 / 4);
  cast_wattn_kernel<<<3072, 256, 0, stream>>>(wa, wab, 3145728 / 4);
  cast_bf16_kernel <<<1024, 256, 0, stream>>>(wp, wpb, 1048576 / 4);

  // qkv = x @ w_attn^T (q pre-scaled): M=8192 N=3072 K=1024 -> bf16
  gemm_bt_kernel<true><<<dim3(3072 / 128, 8192 / 128), 256, 0, stream>>>(
      xb, wab, (void*)qkv, 8192, 3072, 1024);

  // v-part of qkv -> vt [bh*64+d][2048]
  vtrans_kernel<<<dim3(32, 64), 256, 0, stream>>>(qkv, vtb);

  // balanced causal flash attention -> y bf16 [8192,1024]
  attn_kernel<<<dim3(8, 64), 256, 0, stream>>>(qkv, vtb, yb);

  // out = y @ w_proj^T : M=8192 N=1024 K=1024 -> fp32
  gemm_bt_kernel<false><<<dim3(1024 / 128, 8192 / 128), 256, 0, stream>>>(
      yb, wpb, (void*)out, 8192, 1024, 1024);
}

// Round 4
// 276.392 us; speedup vs baseline: 1.7509x; 1.0277x over previous
//
#include <hip/hip_runtime.h>
#include <cstdint>
#include <cstddef>

typedef __attribute__((ext_vector_type(8))) short short8;
typedef __attribute__((ext_vector_type(4))) float f32x4;
typedef unsigned int u32;

#define MFMA_BF16(a, b, c) __builtin_amdgcn_mfma_f32_16x16x32_bf16((a), (b), (c), 0, 0, 0)

// ---------------------------------------------------------------------------
// helpers
// ---------------------------------------------------------------------------
__device__ __forceinline__ void async16(const void* g, void* l) {
  __builtin_amdgcn_global_load_lds(
      (const __attribute__((address_space(1))) u32*)g,
      (__attribute__((address_space(3))) u32*)l, 16, 0, 0);
}

__device__ __forceinline__ short f2bf(float f) {
  u32 u = __builtin_bit_cast(u32, f);
  u += 0x7fffu + ((u >> 16) & 1u);  // round-to-nearest-even
  return (short)(u >> 16);
}

// truncating pack: [bf16(lo) | bf16(hi)<<16] in ONE v_perm_b32
__device__ __forceinline__ u32 pack_bf16_trunc(float lo, float hi) {
  return __builtin_amdgcn_perm(__builtin_bit_cast(u32, hi),
                               __builtin_bit_cast(u32, lo), 0x07060302u);
}

// ---------------------------------------------------------------------------
// cast fp32 -> bf16; scale variant folds attn scale into q-rows of w_attn
// ---------------------------------------------------------------------------
__global__ void cast_bf16_kernel(const float* __restrict__ in,
                                 short* __restrict__ out, int n4) {
  int i = blockIdx.x * blockDim.x + threadIdx.x;
  if (i < n4) {
    float4 v = ((const float4*)in)[i];
    short4 r;
    r.x = f2bf(v.x); r.y = f2bf(v.y); r.z = f2bf(v.z); r.w = f2bf(v.w);
    ((short4*)out)[i] = r;
  }
}

// w_attn [3072][1024]; rows < 1024 (q) scaled by 1/sqrt(64)*log2(e)
__global__ void cast_wattn_kernel(const float* __restrict__ in,
                                  short* __restrict__ out, int n4) {
  int i = blockIdx.x * blockDim.x + threadIdx.x;
  if (i < n4) {
    const float sc = (i * 4 < 1024 * 1024) ? 0.18033688011112042f : 1.0f;
    float4 v = ((const float4*)in)[i];
    short4 r;
    r.x = f2bf(v.x * sc); r.y = f2bf(v.y * sc);
    r.z = f2bf(v.z * sc); r.w = f2bf(v.w * sc);
    ((short4*)out)[i] = r;
  }
}

// ---------------------------------------------------------------------------
// C[M][N] = A[M][K] * Bt[N][K]^T   (bf16-as-short in, fp32 accumulate)
// m97 structure: 128x128 tile, BK=32, global_load_lds w=16, 16x16x32 MFMA.
// ---------------------------------------------------------------------------
template <bool OUT_BF16>
__global__ __launch_bounds__(256) void gemm_bt_kernel(
    const short* __restrict__ A, const short* __restrict__ Bt,
    void* __restrict__ Cv, int M, int N, int K) {
  __shared__ __align__(16) short As[128 * 32];
  __shared__ __align__(16) short Bs[128 * 32];

  const int tid  = threadIdx.x;
  const int lane = tid & 63;
  const int wave = tid >> 6;
  const int quad = lane >> 4;
  const int l15  = lane & 15;
  const int bm   = blockIdx.y * 128;
  const int bn   = blockIdx.x * 128;
  const int wm   = (wave >> 1) * 64;
  const int wn   = (wave & 1) * 64;

  f32x4 acc[4][4];
#pragma unroll
  for (int i = 0; i < 4; ++i)
#pragma unroll
    for (int j = 0; j < 4; ++j) acc[i][j] = (f32x4){0.f, 0.f, 0.f, 0.f};

  const int ci0 = tid, ci1 = tid + 256;
  const short* ga0 = A  + (size_t)(bm + (ci0 >> 2)) * K + (ci0 & 3) * 8;
  const short* ga1 = A  + (size_t)(bm + (ci1 >> 2)) * K + (ci1 & 3) * 8;
  const short* gb0 = Bt + (size_t)(bn + (ci0 >> 2)) * K + (ci0 & 3) * 8;
  const short* gb1 = Bt + (size_t)(bn + (ci1 >> 2)) * K + (ci1 & 3) * 8;

  for (int k0 = 0; k0 < K; k0 += 32) {
    __syncthreads();
    async16(ga0 + k0, &As[ci0 * 8]);
    async16(ga1 + k0, &As[ci1 * 8]);
    async16(gb0 + k0, &Bs[ci0 * 8]);
    async16(gb1 + k0, &Bs[ci1 * 8]);
    __syncthreads();

    short8 af[4], bf[4];
#pragma unroll
    for (int mt = 0; mt < 4; ++mt)
      af[mt] = *(const short8*)&As[(wm + mt * 16 + l15) * 32 + quad * 8];
#pragma unroll
    for (int nt = 0; nt < 4; ++nt)
      bf[nt] = *(const short8*)&Bs[(wn + nt * 16 + l15) * 32 + quad * 8];
#pragma unroll
    for (int mt = 0; mt < 4; ++mt)
#pragma unroll
      for (int nt = 0; nt < 4; ++nt)
        acc[mt][nt] = MFMA_BF16(af[mt], bf[nt], acc[mt][nt]);
  }

#pragma unroll
  for (int mt = 0; mt < 4; ++mt) {
    const int r0 = bm + wm + mt * 16 + quad * 4;
#pragma unroll
    for (int nt = 0; nt < 4; ++nt) {
      const int c = bn + wn + nt * 16 + l15;
#pragma unroll
      for (int reg = 0; reg < 4; ++reg) {
        float v = acc[mt][nt][reg];
        if (OUT_BF16)
          ((short*)Cv)[(size_t)(r0 + reg) * N + c] = f2bf(v);
        else
          ((float*)Cv)[(size_t)(r0 + reg) * N + c] = v;
      }
    }
  }
}

// ---------------------------------------------------------------------------
// V transpose: qkv v-part [B*T][h*64+d] -> vt [bh*64+d][T]   (bf16 shorts)
// ---------------------------------------------------------------------------
__global__ __launch_bounds__(256) void vtrans_kernel(
    const short* __restrict__ qkv, short* __restrict__ vt) {
  __shared__ __align__(16) short Ts[64 * 80];
  const int t0 = blockIdx.x * 64;
  const int bh = blockIdx.y;
  const int b = bh >> 4, h = bh & 15;
  const int tid = threadIdx.x;
#pragma unroll
  for (int it = 0; it < 2; ++it) {
    const int ci = tid + it * 256;
    const int t = ci >> 3, cw = ci & 7;
    short8 v = *(const short8*)(qkv + (size_t)(b * 2048 + t0 + t) * 3072 +
                                2048 + h * 64 + cw * 8);
    *(short8*)&Ts[t * 80 + cw * 8] = v;
  }
  __syncthreads();
#pragma unroll
  for (int it = 0; it < 2; ++it) {
    const int ci = tid + it * 256;
    const int d = ci >> 3, c2 = ci & 7;
    short tmp[8];
#pragma unroll
    for (int j = 0; j < 8; ++j) tmp[j] = Ts[(c2 * 8 + j) * 80 + d];
    *(short8*)(vt + (size_t)(bh * 64 + d) * 2048 + t0 + c2 * 8) =
        *(short8*)tmp;
  }
}

// ---------------------------------------------------------------------------
// Causal flash attention, S^T formulation, no-max softmax, double-buffered
// K/V staging. grid (64 bh, 8 pairi): same-bh blocks differ by 64 in linear
// id == same XCD (round-robin heuristic) -> K/V L2-resident (8 bh x 512 KB
// = 4 MB per XCD). Block = 4 waves, q-tile 128 rows (2 groups of 16/wave),
// kv-tile 64, pair (pairi, 15-pairi) -> 34 equal iterations per block.
// ---------------------------------------------------------------------------
__global__ __launch_bounds__(256, 2) void attn_kernel(
    const short* __restrict__ qkv, const short* __restrict__ vt,
    short* __restrict__ y) {
  __shared__ __align__(16) short Ks[2][2 * 64 * 32];  // [buf][d-half][t][32]
  __shared__ __align__(16) short Vs[2][2 * 64 * 32];  // [buf][t-half][d][32]
  __shared__ __align__(16) short Ps[4][1024];         // per-wave P / epilogue

  const int bh    = blockIdx.x;     // 0..63  (XCD = bh % 8 for all pairi)
  const int pairi = blockIdx.y;     // 0..7
  const int b = bh >> 4, h = bh & 15;
  const int tid  = threadIdx.x;
  const int lane = tid & 63;
  const int wave = tid >> 6;
  const int quad = lane >> 4, l15 = lane & 15;
  const int base_row = b * 2048;
  short* Pw = &Ps[wave][0];
  const int sw = l15 & 3;           // P chunk swizzle (bank spread)

  // staging: ci -> (kk=ci>>8, r=(ci>>2)&63, cw=ci&3), dst=ci*8
  const int ci0 = tid, ci1 = tid + 256;
  const short* kbase0 = qkv + (size_t)(base_row + ((ci0 >> 2) & 63)) * 3072 +
                        1024 + h * 64 + (ci0 >> 8) * 32 + (ci0 & 3) * 8;
  const short* kbase1 = qkv + (size_t)(base_row + ((ci1 >> 2) & 63)) * 3072 +
                        1024 + h * 64 + (ci1 >> 8) * 32 + (ci1 & 3) * 8;
  const short* vbase0 = vt + (size_t)(bh * 64 + ((ci0 >> 2) & 63)) * 2048 +
                        (ci0 >> 8) * 32 + (ci0 & 3) * 8;
  const short* vbase1 = vt + (size_t)(bh * 64 + ((ci1 >> 2) & 63)) * 2048 +
                        (ci1 >> 8) * 32 + (ci1 & 3) * 8;

  for (int half = 0; half < 2; ++half) {
    const int qi  = half ? (15 - pairi) : pairi;
    const int r0  = qi * 128;
    const int nkt = 2 * qi + 2;
    const int qg0a = r0 + wave * 32;   // group 0 q-base (seq-relative)
    const int qg0b = qg0a + 16;        // group 1

    // Q fragments (B-operand): lane holds Q[q=l15][d=quad*8..+7] per half
    short8 qf[2][2];
#pragma unroll
    for (int g = 0; g < 2; ++g) {
      const short* qp = qkv +
          (size_t)(base_row + qg0a + g * 16 + l15) * 3072 + h * 64 + quad * 8;
      qf[g][0] = *(const short8*)qp;
      qf[g][1] = *(const short8*)(qp + 32);
    }
    float l_r[2] = {0.f, 0.f};
    f32x4 o[2][4];
#pragma unroll
    for (int g = 0; g < 2; ++g)
#pragma unroll
      for (int dt = 0; dt < 4; ++dt) o[g][dt] = (f32x4){0.f, 0.f, 0.f, 0.f};

    // prologue: stage kv-tile 0 into buffer 0
    {
      async16(kbase0, &Ks[0][ci0 * 8]);
      async16(kbase1, &Ks[0][ci1 * 8]);
      async16(vbase0, &Vs[0][ci0 * 8]);
      async16(vbase1, &Vs[0][ci1 * 8]);
    }

    for (int kt = 0; kt < nkt; ++kt) {
      const int kvb = kt * 64;
      __syncthreads();  // drains vmcnt -> buf[kt&1] ready; prev reads done

      // prefetch next tile into the other buffer (in flight during compute)
      if (kt + 1 < nkt) {
        const int nb = (kt + 1) & 1;
        const size_t koff = (size_t)(kvb + 64) * 3072;
        async16(kbase0 + koff, &Ks[nb][ci0 * 8]);
        async16(kbase1 + koff, &Ks[nb][ci1 * 8]);
        async16(vbase0 + kvb + 64, &Vs[nb][ci0 * 8]);
        async16(vbase1 + kvb + 64, &Vs[nb][ci1 * 8]);
      }
      const short* Kb = &Ks[kt & 1][0];
      const short* Vb = &Vs[kt & 1][0];

      if (kvb <= qg0b + 15) {  // wave has any unmasked work
        // K fragments (A-operand): lane holds K[kv=nt*16+l15][d=quad*8..]
        short8 kf[4][2];
#pragma unroll
        for (int nt = 0; nt < 4; ++nt) {
          kf[nt][0] = *(const short8*)&Kb[(nt * 16 + l15) * 32 + quad * 8];
          kf[nt][1] = *(const short8*)&Kb[2048 + (nt * 16 + l15) * 32 + quad * 8];
        }
#pragma unroll
        for (int g = 0; g < 2; ++g) {
          const int qg0 = qg0a + g * 16;
          if (kvb > qg0 + 15) continue;  // group fully masked

          // S^T = K Q^T : lane gets S^T[kv=nt*16+quad*4+reg][q=l15]
          f32x4 s[4];
#pragma unroll
          for (int nt = 0; nt < 4; ++nt) {
            s[nt] = MFMA_BF16(kf[nt][0], qf[g][0], ((f32x4){0.f, 0.f, 0.f, 0.f}));
            s[nt] = MFMA_BF16(kf[nt][1], qf[g][1], s[nt]);
          }

          // p = exp2(s) (scale folded into q); mask only on diagonal tiles
          float p[4][4];
          if (kvb + 64 <= qg0) {
#pragma unroll
            for (int nt = 0; nt < 4; ++nt)
#pragma unroll
              for (int r = 0; r < 4; ++r)
                p[nt][r] = __builtin_amdgcn_exp2f(s[nt][r]);
          } else {
            const int qrel = qg0 + l15 - kvb;
#pragma unroll
            for (int nt = 0; nt < 4; ++nt)
#pragma unroll
              for (int r = 0; r < 4; ++r) {
                const int kvl = nt * 16 + quad * 4 + r;
                p[nt][r] = (kvl <= qrel) ? __builtin_amdgcn_exp2f(s[nt][r]) : 0.f;
              }
          }

          // row sum: 15 in-lane adds + 2 cross-quad shuffles
          float rs = ((p[0][0] + p[0][1]) + (p[0][2] + p[0][3])) +
                     ((p[1][0] + p[1][1]) + (p[1][2] + p[1][3])) +
                     ((p[2][0] + p[2][1]) + (p[2][2] + p[2][3])) +
                     ((p[3][0] + p[3][1]) + (p[3][2] + p[3][3]));
          rs += __shfl_xor(rs, 16);
          rs += __shfl_xor(rs, 32);
          l_r[g] += rs;

          // P^T -> LDS [kk][q=l15][32] with XOR chunk swizzle, packed b32
#pragma unroll
          for (int nt = 0; nt < 4; ++nt) {
            u32 w0 = pack_bf16_trunc(p[nt][0], p[nt][1]);
            u32 w1 = pack_bf16_trunc(p[nt][2], p[nt][3]);
            const int chunk = (nt & 1) * 2 + (quad >> 1);
            u32* dst = (u32*)Pw + (nt >> 1) * 256 + l15 * 16 +
                       (chunk ^ sw) * 4 + (quad & 1) * 2;
            dst[0] = w0;
            dst[1] = w1;
          }
          // P fragments (B-operand): lane reads P[q=l15][t=quad*8..] per half
          short8 pf0 = *(const short8*)&Pw[l15 * 32 + (quad ^ sw) * 8];
          short8 pf1 = *(const short8*)&Pw[512 + l15 * 32 + (quad ^ sw) * 8];

          // O^T += V^T P^T : lane gets O^T[d=dt*16+quad*4+reg][q=l15]
#pragma unroll
          for (int dt = 0; dt < 4; ++dt) {
            short8 vf0 = *(const short8*)&Vb[(dt * 16 + l15) * 32 + quad * 8];
            short8 vf1 = *(const short8*)&Vb[2048 + (dt * 16 + l15) * 32 + quad * 8];
            o[g][dt] = MFMA_BF16(vf0, pf0, o[g][dt]);
            o[g][dt] = MFMA_BF16(vf1, pf1, o[g][dt]);
          }
        }
      }
    }

    // epilogue: normalize, transpose via per-wave LDS, coalesced bf16 store
#pragma unroll
    for (int g = 0; g < 2; ++g) {
      const float inv = 1.f / l_r[g];
#pragma unroll
      for (int dt = 0; dt < 4; ++dt) {
        const int d = dt * 16 + quad * 4;
        u32 w0 = pack_bf16_trunc(o[g][dt][0] * inv, o[g][dt][1] * inv);
        u32 w1 = pack_bf16_trunc(o[g][dt][2] * inv, o[g][dt][3] * inv);
        *(uint2*)&Pw[(d >> 5) * 512 + l15 * 32 + (d & 31)] = make_uint2(w0, w1);
      }
      const int qq = lane >> 2, ck = lane & 3;
      const size_t yrow = (size_t)(base_row + qg0a + g * 16 + qq);
#pragma unroll
      for (int kkd = 0; kkd < 2; ++kkd) {
        short8 vv = *(const short8*)&Pw[kkd * 512 + qq * 32 + ck * 8];
        *(short8*)(y + yrow * 1024 + h * 64 + kkd * 32 + ck * 8) = vv;
      }
    }
    __syncthreads();  // all K/V reads of this half done before next prologue
  }
}

// ---------------------------------------------------------------------------
// launch
// ---------------------------------------------------------------------------
extern "C" void kernel_launch(void* const* d_in, const int* in_sizes, int n_in,
                              void* d_out, int out_size, void* d_ws,
                              size_t ws_size, hipStream_t stream) {
  const float* x  = (const float*)d_in[0];   // [4,2048,1024]
  const float* wa = (const float*)d_in[1];   // [3072,1024]
  const float* wp = (const float*)d_in[2];   // [1024,1024]
  float* out = (float*)d_out;                // [4,2048,1024] fp32

  char* ws = (char*)d_ws;
  short* xb  = (short*)(ws + 0);             // 16 MB (reused as vt later)
  short* wab = (short*)(ws + 16777216);      // 6 MB
  short* wpb = (short*)(ws + 23068672);      // 2 MB
  short* qkv = (short*)(ws + 25165824);      // 48 MB
  short* yb  = (short*)(ws + 75497472);      // 16 MB
  short* vtb = xb;  // x no longer needed after GEMM1; reuse its 16 MB

  cast_bf16_kernel <<<8192, 256, 0, stream>>>(x,  xb,  8388608 / 4);
  cast_wattn_kernel<<<3072, 256, 0, stream>>>(wa, wab, 3145728 / 4);
  cast_bf16_kernel <<<1024, 256, 0, stream>>>(wp, wpb, 1048576 / 4);

  // qkv = x @ w_attn^T (q pre-scaled): M=8192 N=3072 K=1024 -> bf16
  gemm_bt_kernel<true><<<dim3(3072 / 128, 8192 / 128), 256, 0, stream>>>(
      xb, wab, (void*)qkv, 8192, 3072, 1024);

  // v-part of qkv -> vt [bh*64+d][2048]
  vtrans_kernel<<<dim3(32, 64), 256, 0, stream>>>(qkv, vtb);

  // balanced causal flash attention -> y bf16 [8192,1024]
  // grid (bh, pairi): same-bh blocks land on one XCD (linear ids mod 8 equal)
  attn_kernel<<<dim3(64, 8), 256, 0, stream>>>(qkv, vtb, yb);

  // out = y @ w_proj^T : M=8192 N=1024 K=1024 -> fp32
  gemm_bt_kernel<false><<<dim3(1024 / 128, 8192 / 128), 256, 0, stream>>>(
      yb, wpb, (void*)out, 8192, 1024, 1024);
}

// Round 5
// 271.408 us; speedup vs baseline: 1.7830x; 1.0184x over previous
//
#include <hip/hip_runtime.h>
#include <cstdint>
#include <cstddef>

typedef __attribute__((ext_vector_type(8))) short short8;
typedef __attribute__((ext_vector_type(4))) float f32x4;
typedef unsigned int u32;

#define MFMA_BF16(a, b, c) __builtin_amdgcn_mfma_f32_16x16x32_bf16((a), (b), (c), 0, 0, 0)

// ---------------------------------------------------------------------------
// helpers
// ---------------------------------------------------------------------------
__device__ __forceinline__ void async16(const void* g, void* l) {
  __builtin_amdgcn_global_load_lds(
      (const __attribute__((address_space(1))) u32*)g,
      (__attribute__((address_space(3))) u32*)l, 16, 0, 0);
}

__device__ __forceinline__ short f2bf(float f) {
  u32 u = __builtin_bit_cast(u32, f);
  u += 0x7fffu + ((u >> 16) & 1u);  // round-to-nearest-even
  return (short)(u >> 16);
}

// truncating pack: [bf16(lo) | bf16(hi)<<16] in ONE v_perm_b32
__device__ __forceinline__ u32 pack_bf16_trunc(float lo, float hi) {
  return __builtin_amdgcn_perm(__builtin_bit_cast(u32, hi),
                               __builtin_bit_cast(u32, lo), 0x07060302u);
}

// ---------------------------------------------------------------------------
// cast fp32 -> bf16; scale variant folds attn scale into q-rows of w_attn
// ---------------------------------------------------------------------------
__global__ void cast_bf16_kernel(const float* __restrict__ in,
                                 short* __restrict__ out, int n4) {
  int i = blockIdx.x * blockDim.x + threadIdx.x;
  if (i < n4) {
    float4 v = ((const float4*)in)[i];
    short4 r;
    r.x = f2bf(v.x); r.y = f2bf(v.y); r.z = f2bf(v.z); r.w = f2bf(v.w);
    ((short4*)out)[i] = r;
  }
}

// w_attn [3072][1024]; rows < 1024 (q) scaled by 1/sqrt(64)*log2(e)
__global__ void cast_wattn_kernel(const float* __restrict__ in,
                                  short* __restrict__ out, int n4) {
  int i = blockIdx.x * blockDim.x + threadIdx.x;
  if (i < n4) {
    const float sc = (i * 4 < 1024 * 1024) ? 0.18033688011112042f : 1.0f;
    float4 v = ((const float4*)in)[i];
    short4 r;
    r.x = f2bf(v.x * sc); r.y = f2bf(v.y * sc);
    r.z = f2bf(v.z * sc); r.w = f2bf(v.w * sc);
    ((short4*)out)[i] = r;
  }
}

// ---------------------------------------------------------------------------
// C[M][N] = A[M][K] * Bt[N][K]^T   (bf16-as-short in, fp32 accumulate)
// m97 structure: 128x128 tile, BK=32, global_load_lds w=16, 16x16x32 MFMA.
// (unchanged from round 4 — known-good)
// ---------------------------------------------------------------------------
template <bool OUT_BF16>
__global__ __launch_bounds__(256) void gemm_bt_kernel(
    const short* __restrict__ A, const short* __restrict__ Bt,
    void* __restrict__ Cv, int M, int N, int K) {
  __shared__ __align__(16) short As[128 * 32];
  __shared__ __align__(16) short Bs[128 * 32];

  const int tid  = threadIdx.x;
  const int lane = tid & 63;
  const int wave = tid >> 6;
  const int quad = lane >> 4;
  const int l15  = lane & 15;
  const int bm   = blockIdx.y * 128;
  const int bn   = blockIdx.x * 128;
  const int wm   = (wave >> 1) * 64;
  const int wn   = (wave & 1) * 64;

  f32x4 acc[4][4];
#pragma unroll
  for (int i = 0; i < 4; ++i)
#pragma unroll
    for (int j = 0; j < 4; ++j) acc[i][j] = (f32x4){0.f, 0.f, 0.f, 0.f};

  const int ci0 = tid, ci1 = tid + 256;
  const short* ga0 = A  + (size_t)(bm + (ci0 >> 2)) * K + (ci0 & 3) * 8;
  const short* ga1 = A  + (size_t)(bm + (ci1 >> 2)) * K + (ci1 & 3) * 8;
  const short* gb0 = Bt + (size_t)(bn + (ci0 >> 2)) * K + (ci0 & 3) * 8;
  const short* gb1 = Bt + (size_t)(bn + (ci1 >> 2)) * K + (ci1 & 3) * 8;

  for (int k0 = 0; k0 < K; k0 += 32) {
    __syncthreads();
    async16(ga0 + k0, &As[ci0 * 8]);
    async16(ga1 + k0, &As[ci1 * 8]);
    async16(gb0 + k0, &Bs[ci0 * 8]);
    async16(gb1 + k0, &Bs[ci1 * 8]);
    __syncthreads();

    short8 af[4], bf[4];
#pragma unroll
    for (int mt = 0; mt < 4; ++mt)
      af[mt] = *(const short8*)&As[(wm + mt * 16 + l15) * 32 + quad * 8];
#pragma unroll
    for (int nt = 0; nt < 4; ++nt)
      bf[nt] = *(const short8*)&Bs[(wn + nt * 16 + l15) * 32 + quad * 8];
#pragma unroll
    for (int mt = 0; mt < 4; ++mt)
#pragma unroll
      for (int nt = 0; nt < 4; ++nt)
        acc[mt][nt] = MFMA_BF16(af[mt], bf[nt], acc[mt][nt]);
  }

#pragma unroll
  for (int mt = 0; mt < 4; ++mt) {
    const int r0 = bm + wm + mt * 16 + quad * 4;
#pragma unroll
    for (int nt = 0; nt < 4; ++nt) {
      const int c = bn + wn + nt * 16 + l15;
#pragma unroll
      for (int reg = 0; reg < 4; ++reg) {
        float v = acc[mt][nt][reg];
        if (OUT_BF16)
          ((short*)Cv)[(size_t)(r0 + reg) * N + c] = f2bf(v);
        else
          ((float*)Cv)[(size_t)(r0 + reg) * N + c] = v;
      }
    }
  }
}

// ---------------------------------------------------------------------------
// V transpose: qkv v-part [B*T][h*64+d] -> vt [bh*64+d][T]   (bf16 shorts)
// (unchanged from round 4 — known-good)
// ---------------------------------------------------------------------------
__global__ __launch_bounds__(256) void vtrans_kernel(
    const short* __restrict__ qkv, short* __restrict__ vt) {
  __shared__ __align__(16) short Ts[64 * 80];
  const int t0 = blockIdx.x * 64;
  const int bh = blockIdx.y;
  const int b = bh >> 4, h = bh & 15;
  const int tid = threadIdx.x;
#pragma unroll
  for (int it = 0; it < 2; ++it) {
    const int ci = tid + it * 256;
    const int t = ci >> 3, cw = ci & 7;
    short8 v = *(const short8*)(qkv + (size_t)(b * 2048 + t0 + t) * 3072 +
                                2048 + h * 64 + cw * 8);
    *(short8*)&Ts[t * 80 + cw * 8] = v;
  }
  __syncthreads();
#pragma unroll
  for (int it = 0; it < 2; ++it) {
    const int ci = tid + it * 256;
    const int d = ci >> 3, c2 = ci & 7;
    short tmp[8];
#pragma unroll
    for (int j = 0; j < 8; ++j) tmp[j] = Ts[(c2 * 8 + j) * 80 + d];
    *(short8*)(vt + (size_t)(bh * 64 + d) * 2048 + t0 + c2 * 8) =
        *(short8*)tmp;
  }
}

// ---------------------------------------------------------------------------
// Causal flash attention, S^T formulation, no-max softmax, dbuf staging,
// XCD-local grid (64 bh, 8 pairi). NEW in r5: conflict-free LDS layouts.
//
// K tile LDS layout: slot ci=(kk<<8)|(nt<<6)|(chunk<<4)|tlo holds
//   K[row = nt*16+tlo][d = kk*32+chunk*8 ..+7]  (16 B)
// frag read kf[nt][kk] @ shorts kk*2048+nt*512+quad*128+l15*8 -> 16-lane
// phase = stride 16 B = 2-way bank alias = free. V analogous (d<->t).
// P per-wave layout: [f(kv/32)][chunk(kv/8&3)][q=l15] x16B; writes are
// 4x ds_write_b64 2-way-free; reads contiguous b128.
// ---------------------------------------------------------------------------
__global__ __launch_bounds__(256, 2) void attn_kernel(
    const short* __restrict__ qkv, const short* __restrict__ vt,
    short* __restrict__ y) {
  __shared__ __align__(16) short Ks[2][4096];  // 8 KB per buf
  __shared__ __align__(16) short Vs[2][4096];
  __shared__ __align__(16) short Ps[4][1024];  // per-wave P / epilogue

  const int bh    = blockIdx.x;     // 0..63  (XCD = bh % 8 for all pairi)
  const int pairi = blockIdx.y;     // 0..7
  const int b = bh >> 4, h = bh & 15;
  const int tid  = threadIdx.x;
  const int lane = tid & 63;
  const int wave = tid >> 6;
  const int quad = lane >> 4, l15 = lane & 15;
  const int base_row = b * 2048;
  short* Pw = &Ps[wave][0];

  // staging: slot ci -> (kk=ci>>8, nt=(ci>>6)&3, chunk=(ci>>4)&3, lo=ci&15)
  const int ci0 = tid, ci1 = tid + 256;
  const int ro0 = ((ci0 >> 6) & 3) * 16 + (ci0 & 15);   // row/d offset
  const int ro1 = ((ci1 >> 6) & 3) * 16 + (ci1 & 15);
  const int co0 = (ci0 >> 8) * 32 + ((ci0 >> 4) & 3) * 8;  // col/t offset
  const int co1 = (ci1 >> 8) * 32 + ((ci1 >> 4) & 3) * 8;
  const short* kbase0 = qkv + (size_t)(base_row + ro0) * 3072 + 1024 + h * 64 + co0;
  const short* kbase1 = qkv + (size_t)(base_row + ro1) * 3072 + 1024 + h * 64 + co1;
  const short* vbase0 = vt + (size_t)(bh * 64 + ro0) * 2048 + co0;
  const short* vbase1 = vt + (size_t)(bh * 64 + ro1) * 2048 + co1;

  for (int half = 0; half < 2; ++half) {
    const int qi  = half ? (15 - pairi) : pairi;
    const int r0  = qi * 128;
    const int nkt = 2 * qi + 2;
    const int qg0a = r0 + wave * 32;   // group 0 q-base (seq-relative)
    const int qg0b = qg0a + 16;        // group 1

    // Q fragments (B-operand): lane holds Q[q=l15][d=quad*8..+7] per half
    short8 qf[2][2];
#pragma unroll
    for (int g = 0; g < 2; ++g) {
      const short* qp = qkv +
          (size_t)(base_row + qg0a + g * 16 + l15) * 3072 + h * 64 + quad * 8;
      qf[g][0] = *(const short8*)qp;
      qf[g][1] = *(const short8*)(qp + 32);
    }
    float l_r[2] = {0.f, 0.f};
    f32x4 o[2][4];
#pragma unroll
    for (int g = 0; g < 2; ++g)
#pragma unroll
      for (int dt = 0; dt < 4; ++dt) o[g][dt] = (f32x4){0.f, 0.f, 0.f, 0.f};

    // prologue: stage kv-tile 0 into buffer 0
    async16(kbase0, &Ks[0][ci0 * 8]);
    async16(kbase1, &Ks[0][ci1 * 8]);
    async16(vbase0, &Vs[0][ci0 * 8]);
    async16(vbase1, &Vs[0][ci1 * 8]);

    for (int kt = 0; kt < nkt; ++kt) {
      const int kvb = kt * 64;
      __syncthreads();  // drains vmcnt -> buf[kt&1] ready; prev reads done

      // prefetch next tile into the other buffer
      if (kt + 1 < nkt) {
        const int nb = (kt + 1) & 1;
        const size_t koff = (size_t)(kvb + 64) * 3072;
        async16(kbase0 + koff, &Ks[nb][ci0 * 8]);
        async16(kbase1 + koff, &Ks[nb][ci1 * 8]);
        async16(vbase0 + kvb + 64, &Vs[nb][ci0 * 8]);
        async16(vbase1 + kvb + 64, &Vs[nb][ci1 * 8]);
      }
      const short* Kb = &Ks[kt & 1][0];
      const short* Vb = &Vs[kt & 1][0];

      // K frags (A-operand): conflict-free reads
      short8 kf[4][2];
#pragma unroll
      for (int nt = 0; nt < 4; ++nt) {
        kf[nt][0] = *(const short8*)&Kb[nt * 512 + quad * 128 + l15 * 8];
        kf[nt][1] = *(const short8*)&Kb[2048 + nt * 512 + quad * 128 + l15 * 8];
      }
      // V frags (A-operand): hoisted — read ONCE, shared by both groups
      short8 vf[4][2];
#pragma unroll
      for (int dt = 0; dt < 4; ++dt) {
        vf[dt][0] = *(const short8*)&Vb[dt * 512 + quad * 128 + l15 * 8];
        vf[dt][1] = *(const short8*)&Vb[2048 + dt * 512 + quad * 128 + l15 * 8];
      }

#pragma unroll
      for (int g = 0; g < 2; ++g) {
        const int qg0 = qg0a + g * 16;
        if (kvb > qg0 + 15) continue;  // group fully masked

        // S^T = K Q^T : lane gets S^T[kv=nt*16+quad*4+reg][q=l15]
        f32x4 s[4];
#pragma unroll
        for (int nt = 0; nt < 4; ++nt) {
          s[nt] = MFMA_BF16(kf[nt][0], qf[g][0], ((f32x4){0.f, 0.f, 0.f, 0.f}));
          s[nt] = MFMA_BF16(kf[nt][1], qf[g][1], s[nt]);
        }

        // p = exp2(s); mask only on diagonal tiles
        float p[4][4];
        if (kvb + 64 <= qg0) {
#pragma unroll
          for (int nt = 0; nt < 4; ++nt)
#pragma unroll
            for (int r = 0; r < 4; ++r)
              p[nt][r] = __builtin_amdgcn_exp2f(s[nt][r]);
        } else {
          const int qrel = qg0 + l15 - kvb;
#pragma unroll
          for (int nt = 0; nt < 4; ++nt)
#pragma unroll
            for (int r = 0; r < 4; ++r) {
              const int kvl = nt * 16 + quad * 4 + r;
              p[nt][r] = (kvl <= qrel) ? __builtin_amdgcn_exp2f(s[nt][r]) : 0.f;
            }
        }

        // row sum: 15 in-lane adds + 2 cross-quad shuffles
        float rs = ((p[0][0] + p[0][1]) + (p[0][2] + p[0][3])) +
                   ((p[1][0] + p[1][1]) + (p[1][2] + p[1][3])) +
                   ((p[2][0] + p[2][1]) + (p[2][2] + p[2][3])) +
                   ((p[3][0] + p[3][1]) + (p[3][2] + p[3][3]));
        rs += __shfl_xor(rs, 16);
        rs += __shfl_xor(rs, 32);
        l_r[g] += rs;

        // P -> LDS, layout [f][chunk][q]x16B; pair p0 = 8nt+2quad
        // word idx = f*256 + chunk*64 + l15*4 + (p0&3); idx1 = idx0+1
#pragma unroll
        for (int nt = 0; nt < 4; ++nt) {
          u32 w0 = pack_bf16_trunc(p[nt][0], p[nt][1]);
          u32 w1 = pack_bf16_trunc(p[nt][2], p[nt][3]);
          const int p0 = 8 * nt + 2 * quad;
          u32* dst = (u32*)Pw + (p0 >> 4) * 256 + ((p0 >> 2) & 3) * 64 +
                     l15 * 4 + (p0 & 3);
          *(uint2*)dst = make_uint2(w0, w1);
        }
        // P frags (B-operand): contiguous b128, conflict-free
        short8 pf0 = *(const short8*)&Pw[quad * 128 + l15 * 8];
        short8 pf1 = *(const short8*)&Pw[512 + quad * 128 + l15 * 8];

        // O^T += V^T P^T : lane gets O^T[d=dt*16+quad*4+reg][q=l15]
#pragma unroll
        for (int dt = 0; dt < 4; ++dt) {
          o[g][dt] = MFMA_BF16(vf[dt][0], pf0, o[g][dt]);
          o[g][dt] = MFMA_BF16(vf[dt][1], pf1, o[g][dt]);
        }
      }
    }

    // epilogue: normalize, transpose via per-wave LDS, coalesced bf16 store
#pragma unroll
    for (int g = 0; g < 2; ++g) {
      const float inv = 1.f / l_r[g];
#pragma unroll
      for (int dt = 0; dt < 4; ++dt) {
        const int d = dt * 16 + quad * 4;
        u32 w0 = pack_bf16_trunc(o[g][dt][0] * inv, o[g][dt][1] * inv);
        u32 w1 = pack_bf16_trunc(o[g][dt][2] * inv, o[g][dt][3] * inv);
        *(uint2*)&Pw[(d >> 5) * 512 + l15 * 32 + (d & 31)] = make_uint2(w0, w1);
      }
      const int qq = lane >> 2, ck = lane & 3;
      const size_t yrow = (size_t)(base_row + qg0a + g * 16 + qq);
#pragma unroll
      for (int kkd = 0; kkd < 2; ++kkd) {
        short8 vv = *(const short8*)&Pw[kkd * 512 + qq * 32 + ck * 8];
        *(short8*)(y + yrow * 1024 + h * 64 + kkd * 32 + ck * 8) = vv;
      }
    }
    __syncthreads();  // all K/V/P reads of this half done before next prologue
  }
}

// ---------------------------------------------------------------------------
// launch
// ---------------------------------------------------------------------------
extern "C" void kernel_launch(void* const* d_in, const int* in_sizes, int n_in,
                              void* d_out, int out_size, void* d_ws,
                              size_t ws_size, hipStream_t stream) {
  const float* x  = (const float*)d_in[0];   // [4,2048,1024]
  const float* wa = (const float*)d_in[1];   // [3072,1024]
  const float* wp = (const float*)d_in[2];   // [1024,1024]
  float* out = (float*)d_out;                // [4,2048,1024] fp32

  char* ws = (char*)d_ws;
  short* xb  = (short*)(ws + 0);             // 16 MB (reused as vt later)
  short* wab = (short*)(ws + 16777216);      // 6 MB
  short* wpb = (short*)(ws + 23068672);      // 2 MB
  short* qkv = (short*)(ws + 25165824);      // 48 MB
  short* yb  = (short*)(ws + 75497472);      // 16 MB
  short* vtb = xb;  // x no longer needed after GEMM1; reuse its 16 MB

  cast_bf16_kernel <<<8192, 256, 0, stream>>>(x,  xb,  8388608 / 4);
  cast_wattn_kernel<<<3072, 256, 0, stream>>>(wa, wab, 3145728 / 4);
  cast_bf16_kernel <<<1024, 256, 0, stream>>>(wp, wpb, 1048576 / 4);

  // qkv = x @ w_attn^T (q pre-scaled): M=8192 N=3072 K=1024 -> bf16
  gemm_bt_kernel<true><<<dim3(3072 / 128, 8192 / 128), 256, 0, stream>>>(
      xb, wab, (void*)qkv, 8192, 3072, 1024);

  // v-part of qkv -> vt [bh*64+d][2048]
  vtrans_kernel<<<dim3(32, 64), 256, 0, stream>>>(qkv, vtb);

  // balanced causal flash attention -> y bf16 [8192,1024]
  attn_kernel<<<dim3(64, 8), 256, 0, stream>>>(qkv, vtb, yb);

  // out = y @ w_proj^T : M=8192 N=1024 K=1024 -> fp32
  gemm_bt_kernel<false><<<dim3(1024 / 128, 8192 / 128), 256, 0, stream>>>(
      yb, wpb, (void*)out, 8192, 1024, 1024);
}